// Round 3
// baseline (210.935 us; speedup 1.0000x reference)
//
#include <hip/hip_runtime.h>
#include <hip/hip_bf16.h>

#define B_    1024
#define N_    128
#define FEAT_ 512
#define HID_  256

typedef __bf16 bf16x8 __attribute__((ext_vector_type(8)));
typedef float  f32x4  __attribute__((ext_vector_type(4)));

__device__ __forceinline__ unsigned int f2bf(float f) {
    unsigned int u = __float_as_uint(f);
    u += 0x7fffu + ((u >> 16) & 1u);   // round-to-nearest-even
    return u >> 16;
}
__device__ __forceinline__ unsigned int pack2(float a, float b) {
    return f2bf(a) | (f2bf(b) << 16);
}

// ---------------- prep: conv (blocks 0..2047) + proj (blocks 2048..2559), 256 thr ----------------
// (256,6): 6 blocks/CU (24 waves) for conv streaming TLP; VGPR cap 85 leaves room for
//   proj's pipeline. Round-2 lesson: (512,4) = 2 blocks/CU starved conv (prep ~29.5us).
// conv (round-0-proven): 16-row tile (n, jg). Thread owns 2 granules: 32B fp32 load ->
//   uint4 store at swizzled granule g2 = gc ^ ((j&7)<<2). sv[16][33] + shuffles produce
//   v2[j] = 2*sum_k mu_k M[j,k]; cpart[n*16+jg] = block partial of mu^T M mu.
// proj: 2 b-rows/block, thread owns 2 consecutive h (float2 W loads, 512B/wave-instr),
//   8-deep A/B register prefetch = only 32 buffer VGPRs (fits the 85 cap; round-1's
//   collapse was 128 VGPR of buffers under a 64 cap).
__global__ __launch_bounds__(256, 6) void prep_kernel(
    const float* __restrict__ x, const float* __restrict__ W,
    const float* __restrict__ bias, const float* __restrict__ means,
    const float* __restrict__ invcov,
    float* __restrict__ xp, unsigned short* __restrict__ xbf,
    unsigned short* __restrict__ Mbf, float* __restrict__ v2,
    float* __restrict__ cpart, float* __restrict__ out)
{
    const int t = threadIdx.x;
    if (blockIdx.x < 2048) {
        // ---------------- conv role ----------------
        __shared__ float sv[16][33];
        __shared__ float sw[2];
        const int cb = blockIdx.x;         // 0..2047
        const int n  = cb >> 4;            // 0..127
        const int jg = cb & 15;            // 16-row group
        const float* Mn = invcov + (size_t)n * (HID_ * HID_) + (size_t)jg * 16 * HID_;
        const float* mu = means + (size_t)n * HID_;
        unsigned short* Mb = Mbf + (size_t)n * (HID_ * HID_) + (size_t)jg * 16 * HID_;
        const int gc = t & 31;             // granule column (k = gc*8 .. gc*8+7)
        const int r0 = t >> 5;             // 0..7 -> rows r0 and r0+8
        const float4 mk0 = *(const float4*)(mu + gc * 8);
        const float4 mk1 = *(const float4*)(mu + gc * 8 + 4);
        if (cb == 0 && t == 0) out[0] = (float)(N_ - 1) * 1e-12f;   // clip residue init
        #pragma unroll
        for (int i = 0; i < 2; ++i) {
            const int row = r0 + i * 8;    // local 0..15; global j = jg*16+row, j&7 == row&7
            const float* src = Mn + (size_t)row * HID_ + gc * 8;
            const float4 a = *(const float4*)src;
            const float4 b = *(const float4*)(src + 4);
            const int g2 = gc ^ ((row & 7) << 2);
            *(uint4*)(Mb + (size_t)row * HID_ + g2 * 8) =
                make_uint4(pack2(a.x, a.y), pack2(a.z, a.w), pack2(b.x, b.y), pack2(b.z, b.w));
            sv[row][gc] = a.x * mk0.x + a.y * mk0.y + a.z * mk0.z + a.w * mk0.w
                        + b.x * mk1.x + b.y * mk1.y + b.z * mk1.z + b.w * mk1.w;
        }
        __syncthreads();
        if (t < 128) {
            const int row = t >> 3;        // 0..15 (8 per wave)
            const int i0  = (t & 7) * 4;
            float v = sv[row][i0] + sv[row][i0 + 1] + sv[row][i0 + 2] + sv[row][i0 + 3];
            v += __shfl_xor(v, 1);         // reduce across the 8 gc-groups
            v += __shfl_xor(v, 2);
            v += __shfl_xor(v, 4);
            const int j = jg * 16 + row;
            if ((t & 7) == 0) v2[(size_t)n * HID_ + j] = 2.f * v;
            float cc = ((t & 7) == 0) ? v * mu[j] : 0.f;
            cc += __shfl_xor(cc, 8);       // sum the 8 rows of this wave
            cc += __shfl_xor(cc, 16);
            cc += __shfl_xor(cc, 32);
            if ((t & 63) == 0) sw[t >> 6] = cc;
        }
        __syncthreads();
        if (t == 0) cpart[cb] = sw[0] + sw[1];
    } else {
        // ---------------- proj role ----------------
        __shared__ float xs[2][FEAT_];          // 4 KB
        const int pb = blockIdx.x - 2048;       // 0..511
        const int b0 = pb * 2;
        ((float4*)&xs[0][0])[t] = ((const float4*)(x + (size_t)b0 * FEAT_))[t];  // 256 float4
        __syncthreads();
        const int row = t >> 7;                 // 0..1 (waves 0,1 -> row 0; 2,3 -> row 1)
        const int h2  = t & 127;                // float2 column (h = 2*h2, 2*h2+1)
        const float* __restrict__ xr = &xs[row][0];
        const float2* Wv = (const float2*)W;    // [512][128] float2
        float2 acc = ((const float2*)bias)[h2];
        float2 Ab[8], Bb[8];                    // A/B prefetch, 16 VGPR each
        auto LD = [&](float2 (&buf)[8], int g) {
            #pragma unroll
            for (int u = 0; u < 8; ++u) buf[u] = Wv[(size_t)(g * 8 + u) * 128 + h2];
        };
        auto FM = [&](const float2 (&buf)[8], int g) {
            #pragma unroll
            for (int u = 0; u < 8; ++u) {
                const float xv = xr[g * 8 + u];
                acc.x += xv * buf[u].x;
                acc.y += xv * buf[u].y;
            }
        };
        LD(Ab, 0);
        for (int g = 0; g < 62; g += 2) {       // 64 windows of 8 f
            LD(Bb, g + 1);
            FM(Ab, g);
            LD(Ab, g + 2);
            FM(Bb, g + 1);
        }
        LD(Bb, 63);
        FM(Ab, 62);
        FM(Bb, 63);
        const int gr = b0 + row;
        ((float2*)(xp + (size_t)gr * HID_))[h2] = acc;
        *(unsigned int*)(xbf + (size_t)gr * HID_ + h2 * 2) = pack2(acc.x, acc.y);
    }
}

// ---------------- dist (+fused finalize/loss) ----------------
// Per block: full n-column for 256 b-rows. distmat[b,n] = sqrt(sum_j (T[b,j]-v2[n,j])*xp[b,j]
//   + cn + 1e-12), T = x.M_n (bf16 MFMA, fp32 acc), cn = mu^T M mu.
// grid (4 bh, 128 n) = 512 blocks x 512 thr, LDS = 2 x 32KB dbuf -> 2 blocks/CU ->
//   EXACTLY one resident round (no round-2 DMA tail). 4 phases of 64 j-rows: issue
//   DMA(p+1) first, compute phase p (4 ct x {8 ds_read_b128 2-way-free + 16 MFMA}),
//   barrier (its vmcnt drain = exactly the DMA(p+1) completion we need -> free overlap).
// v2 loaded per-phase (v2p[4]) to keep VGPR ~112 < 128 cap (no spill).
// Epilogue: cross-lane reduce, d=sqrt(...), write distmat, label-matched atomicAdd
//   (per-block ~2 matches) onto out[0] (pre-init by prep). p-buffer + finalize launch gone.
__global__ __launch_bounds__(512, 4) void dist_kernel(
    const float* __restrict__ xp, const unsigned short* __restrict__ xbf,
    const unsigned short* __restrict__ Mbf, const float* __restrict__ v2,
    const float* __restrict__ cpart, const int* __restrict__ labels,
    float* __restrict__ out)
{
    extern __shared__ unsigned short Ms[];   // 2 x 16384 shorts (2 x 32 KB)
    __shared__ float cn;

    const int tid  = threadIdx.x;
    const int bh   = blockIdx.x;       // 0..3
    const int n    = blockIdx.y;       // 0..127
    const int wave = tid >> 6;
    const int lane = tid & 63;
    const int q    = lane >> 4;        // quad 0..3
    const int l    = lane & 15;

    // ---- DMA stage phase 0 (32 KB = 32 chunks of 1 KB) ----
    const unsigned short* src = Mbf + (size_t)n * (HID_ * HID_);
    #pragma unroll
    for (int i = 0; i < 4; ++i) {
        const int c = i * 8 + wave;    // chunk id, wave-uniform
        __builtin_amdgcn_global_load_lds(
            (const __attribute__((address_space(1))) unsigned int*)(src + (size_t)c * 512 + lane * 8),
            (__attribute__((address_space(3))) unsigned int*)&Ms[c * 512],
            16, 0, 0);
    }
    // cn = mu^T M mu (16 group-partials), overlapped with the DMA
    if (tid == 0) {
        float s = 0.f;
        #pragma unroll
        for (int g = 0; g < 16; ++g) s += cpart[n * 16 + g];
        cn = s;
    }

    // ---- afrag: x rows (bf16, pre-converted), full K=256, 2 row-blocks of 16 ----
    // A layout: A[m=lane&15][k=quad*8+j]
    bf16x8 afrag[2][8];
    #pragma unroll
    for (int rb = 0; rb < 2; ++rb) {
        const unsigned short* xr = xbf + (size_t)(bh * 256 + wave * 32 + rb * 16 + l) * HID_;
        #pragma unroll
        for (int kk = 0; kk < 8; ++kk)
            afrag[rb][kk] = *(const bf16x8*)(xr + kk * 32 + q * 8);
    }

    __syncthreads();   // phase-0 DMA drained (vmcnt), cn visible

    float part[8];
    #pragma unroll
    for (int i = 0; i < 8; ++i) part[i] = 0.f;

    // epilogue x source: row (bh*256 + wave*32 + q*4 + r + rb*16), col (ct*16 + l)
    const size_t xbase = (size_t)(bh * 256 + wave * 32 + q * 4) * HID_ + l;

    #pragma unroll
    for (int p = 0; p < 4; ++p) {
        // issue next-phase DMA into the other buffer (written buf untouched this phase)
        if (p < 3) {
            const unsigned short* sp = src + (size_t)(p + 1) * 16384;
            #pragma unroll
            for (int i = 0; i < 4; ++i) {
                const int c = i * 8 + wave;
                __builtin_amdgcn_global_load_lds(
                    (const __attribute__((address_space(1))) unsigned int*)(sp + (size_t)c * 512 + lane * 8),
                    (__attribute__((address_space(3))) unsigned int*)&Ms[((p + 1) & 1) * 16384 + c * 512],
                    16, 0, 0);
            }
        }
        // v2 for this phase's 4 ct (j = ct*16 + l)
        float v2p[4];
        #pragma unroll
        for (int ctl = 0; ctl < 4; ++ctl)
            v2p[ctl] = v2[(size_t)n * HID_ + (p * 4 + ctl) * 16 + l];

        #pragma unroll
        for (int ctl = 0; ctl < 4; ++ctl) {
            const int ct = p * 4 + ctl;
            // hoist fp32 x loads for the fused epilogue
            float xl[8];
            #pragma unroll
            for (int rb = 0; rb < 2; ++rb)
                #pragma unroll
                for (int r = 0; r < 4; ++r)
                    xl[rb * 4 + r] = xp[xbase + (size_t)(rb * 16 + r) * HID_ + ct * 16];

            f32x4 acc0 = {0.f,0.f,0.f,0.f}, acc1 = {0.f,0.f,0.f,0.f};
            #pragma unroll
            for (int kk = 0; kk < 8; ++kk) {
                // swizzled read: row jr=ctl*16+l, granule (kk*4+q)^((l&7)<<2) -> 2-way banks (free)
                const bf16x8 bfrag = *(const bf16x8*)&Ms[(p & 1) * 16384 + (ctl * 16 + l) * HID_ +
                                                         (((kk * 4 + q) ^ ((l & 7) << 2)) << 3)];
                acc0 = __builtin_amdgcn_mfma_f32_16x16x32_bf16(afrag[0][kk], bfrag, acc0, 0, 0, 0);
                acc1 = __builtin_amdgcn_mfma_f32_16x16x32_bf16(afrag[1][kk], bfrag, acc1, 0, 0, 0);
            }
            // fused epilogue: part += (T - v2) * x   (C/D layout: col=lane&15, row=quad*4+reg)
            const float vv = v2p[ctl];
            #pragma unroll
            for (int r = 0; r < 4; ++r) {
                part[r]     += (acc0[r] - vv) * xl[r];
                part[4 + r] += (acc1[r] - vv) * xl[4 + r];
            }
        }
        if (p < 3) __syncthreads();   // vmcnt drain = DMA(p+1) complete; buffers swap
    }

    // reduce across the 16 col-lanes of each quad
    #pragma unroll
    for (int i = 0; i < 8; ++i) {
        float v = part[i];
        v += __shfl_xor(v, 1);
        v += __shfl_xor(v, 2);
        v += __shfl_xor(v, 4);
        v += __shfl_xor(v, 8);
        part[i] = v;
    }
    if (l == 0) {
        const float cc = cn;
        #pragma unroll
        for (int i = 0; i < 8; ++i) {
            const int row = bh * 256 + wave * 32 + (i >> 2) * 16 + q * 4 + (i & 3);
            const float d = sqrtf(part[i] + cc + 1e-12f);
            out[1 + (size_t)row * N_ + n] = d;
            if (labels[row] == n) atomicAdd(out, d * (1.f / (float)B_));
        }
    }
}

extern "C" void kernel_launch(void* const* d_in, const int* in_sizes, int n_in,
                              void* d_out, int out_size, void* d_ws, size_t ws_size,
                              hipStream_t stream) {
    const float* x      = (const float*)d_in[0];
    const int*   labels = (const int*)d_in[1];
    const float* W      = (const float*)d_in[2];
    const float* bias   = (const float*)d_in[3];
    const float* means  = (const float*)d_in[4];
    const float* invcov = (const float*)d_in[5];
    float* out = (float*)d_out;

    // workspace carve-up (~18.5 MB total)
    char* ws = (char*)d_ws;
    unsigned short* Mbf   = (unsigned short*)(ws);               // 16,777,216 B
    float*          xp    = (float*)         (ws + 16777216);    //  1,048,576 B
    unsigned short* xbf   = (unsigned short*)(ws + 17825792);    //    524,288 B
    float*          v2    = (float*)         (ws + 18350080);    //    131,072 B
    float*          cpart = (float*)         (ws + 18481152);    //      8,192 B

    constexpr int DIST_LDS = 2 * 16384 * 2;    // 65536 B dynamic LDS (2 x 32KB dbuf)
    (void)hipFuncSetAttribute((const void*)dist_kernel,
                              hipFuncAttributeMaxDynamicSharedMemorySize, DIST_LDS);

    prep_kernel<<<dim3(2560), 256, 0, stream>>>(x, W, bias, means, invcov,
                                                xp, xbf, Mbf, v2, cpart, out);
    dist_kernel<<<dim3(4, N_), 512, DIST_LDS, stream>>>(xp, xbf, Mbf, v2,
                                                        cpart, labels, out);
}

// Round 4
// 154.408 us; speedup vs baseline: 1.3661x; 1.3661x over previous
//
#include <hip/hip_runtime.h>
#include <hip/hip_bf16.h>

#define B_    1024
#define N_    128
#define FEAT_ 512
#define HID_  256

typedef __bf16 bf16x8 __attribute__((ext_vector_type(8)));
typedef float  f32x4  __attribute__((ext_vector_type(4)));

__device__ __forceinline__ unsigned int f2bf(float f) {
    unsigned int u = __float_as_uint(f);
    u += 0x7fffu + ((u >> 16) & 1u);   // round-to-nearest-even
    return u >> 16;
}
__device__ __forceinline__ unsigned int pack2(float a, float b) {
    return f2bf(a) | (f2bf(b) << 16);
}

// ---------------- prep: proj (blocks 0..127) + conv (blocks 128..1151), 512 thr ----------------
// proj W-amplification fix (rounds 0-3 all ~35-44us): every proj block reads the FULL
//   512 KB W; r2's 512 blocks = 256 MB logical W traffic from L3/HBM (fills+conv evict
//   L2) -> ~30us tail. Now: block = 16 b-rows x 128 h-cols -> 128 blocks x 256 KB slice
//   = 32 MB (8x less). wave = 2 rows (wave-uniform x broadcast), lane = float2 of h
//   (512 B/instr coalesced W), 8-deep A/B prefetch = 32 buf VGPR (~70 total < 128 cap).
//   Proj blocks dispatched FIRST to overlap conv.
// conv (round-2-proven, shifted): 32-row tile (n, jg2). Thread owns 2 granules: 32B fp32
//   load -> uint4 store at swizzled granule g2 = gc ^ ((j&7)<<2) ((r0+16i)&7 == r0&7).
//   sv[32][33] + shuffles -> v2[j] = 2*sum_k mu_k M[j,k]; cpart[n*8+jg2] = mu^T M mu part.
__global__ __launch_bounds__(512, 4) void prep_kernel(
    const float* __restrict__ x, const float* __restrict__ W,
    const float* __restrict__ bias, const float* __restrict__ means,
    const float* __restrict__ invcov,
    float* __restrict__ xp, unsigned short* __restrict__ xbf,
    unsigned short* __restrict__ Mbf, float* __restrict__ v2,
    float* __restrict__ cpart, float* __restrict__ out)
{
    __shared__ float smem[16 * FEAT_];          // 32 KB, carved per role
    const int t = threadIdx.x;
    if (blockIdx.x < 128) {
        // ---------------- proj role ----------------
        float (*xs)[FEAT_] = (float (*)[FEAT_])smem;   // [16][512]
        const int pb    = blockIdx.x;           // 0..127
        const int b0    = (pb >> 1) * 16;       // 16-row group
        const int hbase = (pb & 1) * 128;       // h half
        {
            const float4* xsrc = (const float4*)(x + (size_t)b0 * FEAT_);  // 2048 float4
            #pragma unroll
            for (int i = 0; i < 4; ++i)
                ((float4*)smem)[t + i * 512] = xsrc[t + i * 512];
        }
        if (pb == 0 && t == 0) out[0] = (float)(N_ - 1) * 1e-12f;   // clip residue init
        __syncthreads();
        const int w = t >> 6;                   // wave 0..7 -> local rows 2w, 2w+1
        const int l = t & 63;                   // float2 col: h = hbase + 2l, 2l+1
        const float* __restrict__ xr0 = &xs[w * 2][0];
        const float* __restrict__ xr1 = &xs[w * 2 + 1][0];
        const float2* Wp = (const float2*)(W + hbase);  // row stride 128 float2
        float2 a0 = ((const float2*)(bias + hbase))[l];
        float2 a1 = a0;
        float2 Ab[8], Bb[8];                    // A/B prefetch, 16 VGPR each
        auto LD = [&](float2 (&buf)[8], int g) {
            #pragma unroll
            for (int u = 0; u < 8; ++u) buf[u] = Wp[(size_t)(g * 8 + u) * 128 + l];
        };
        auto FM = [&](const float2 (&buf)[8], int g) {
            #pragma unroll
            for (int u = 0; u < 8; ++u) {
                const float x0 = xr0[g * 8 + u];
                const float x1 = xr1[g * 8 + u];
                a0.x += x0 * buf[u].x;  a0.y += x0 * buf[u].y;
                a1.x += x1 * buf[u].x;  a1.y += x1 * buf[u].y;
            }
        };
        LD(Ab, 0);
        for (int g = 0; g < 62; g += 2) {       // 64 windows of 8 f
            LD(Bb, g + 1);
            FM(Ab, g);
            LD(Ab, g + 2);
            FM(Bb, g + 1);
        }
        LD(Bb, 63);
        FM(Ab, 62);
        FM(Bb, 63);
        const int r0g = b0 + w * 2;
        ((float2*)(xp + (size_t)r0g * HID_ + hbase))[l]       = a0;
        ((float2*)(xp + (size_t)(r0g + 1) * HID_ + hbase))[l] = a1;
        *(unsigned int*)(xbf + (size_t)r0g * HID_ + hbase + l * 2)       = pack2(a0.x, a0.y);
        *(unsigned int*)(xbf + (size_t)(r0g + 1) * HID_ + hbase + l * 2) = pack2(a1.x, a1.y);
    } else {
        // ---------------- conv role ----------------
        float (*sv)[33] = (float (*)[33])smem;          // [32][33]
        float* sw = smem + 32 * 33;                     // [4]
        const int cb  = blockIdx.x - 128;  // 0..1023
        const int n   = cb >> 3;           // 0..127
        const int jg2 = cb & 7;            // 32-row group
        const float* Mn = invcov + (size_t)n * (HID_ * HID_) + (size_t)jg2 * 32 * HID_;
        const float* mu = means + (size_t)n * HID_;
        unsigned short* Mb = Mbf + (size_t)n * (HID_ * HID_) + (size_t)jg2 * 32 * HID_;
        const int gc = t & 31;             // granule column (k = gc*8 .. gc*8+7)
        const int r0 = t >> 5;             // 0..15 -> rows r0 and r0+16
        const float4 mk0 = *(const float4*)(mu + gc * 8);
        const float4 mk1 = *(const float4*)(mu + gc * 8 + 4);
        #pragma unroll
        for (int i = 0; i < 2; ++i) {
            const int row = r0 + i * 16;   // local 0..31; global j = jg2*32+row, j&7 == row&7
            const float* src = Mn + (size_t)row * HID_ + gc * 8;
            const float4 a = *(const float4*)src;
            const float4 b = *(const float4*)(src + 4);
            const int g2 = gc ^ ((row & 7) << 2);
            *(uint4*)(Mb + (size_t)row * HID_ + g2 * 8) =
                make_uint4(pack2(a.x, a.y), pack2(a.z, a.w), pack2(b.x, b.y), pack2(b.z, b.w));
            sv[row][gc] = a.x * mk0.x + a.y * mk0.y + a.z * mk0.z + a.w * mk0.w
                        + b.x * mk1.x + b.y * mk1.y + b.z * mk1.z + b.w * mk1.w;
        }
        __syncthreads();
        if (t < 256) {
            const int row = t >> 3;        // 0..31 (8 rows per wave)
            const int i0  = (t & 7) * 4;
            float v = sv[row][i0] + sv[row][i0 + 1] + sv[row][i0 + 2] + sv[row][i0 + 3];
            v += __shfl_xor(v, 1);         // reduce across the 8 gc-groups
            v += __shfl_xor(v, 2);
            v += __shfl_xor(v, 4);
            const int j = jg2 * 32 + row;
            if ((t & 7) == 0) v2[(size_t)n * HID_ + j] = 2.f * v;
            float cc = ((t & 7) == 0) ? v * mu[j] : 0.f;
            cc += __shfl_xor(cc, 8);       // sum the 8 rows of this wave
            cc += __shfl_xor(cc, 16);
            cc += __shfl_xor(cc, 32);
            if ((t & 63) == 0) sw[t >> 6] = cc;
        }
        __syncthreads();
        if (t == 0) cpart[cb] = sw[0] + sw[1] + sw[2] + sw[3];
    }
}

// ---------------- dist: p[jh][b][n] = sum_{j in half} (T[b,j] - v2[n,j]) * xp[b,j] ----------------
// Round-2 known-good version, verbatim. T = x . M_n (bf16 MFMA, fp32 acc). grid
// (4 bg, 2 jh, 128 n) = 1024 blocks, 512 threads, 64 KB LDS -> 2 blocks/CU. M-half
// staged by pure global_load_lds DMA (pre-converted, pre-swizzled bf16). Wave owns 32
// b-rows; afrag resident in 64 regs; per ct: 8 ds_read_b128 (2-way only) + 16 MFMA.
__global__ __launch_bounds__(512, 4) void dist_kernel(
    const float* __restrict__ xp, const unsigned short* __restrict__ xbf,
    const unsigned short* __restrict__ Mbf, const float* __restrict__ v2,
    float* __restrict__ p)
{
    extern __shared__ unsigned short Ms[];   // 128 rows x 256 el (swizzled) = 65536 B

    const int tid  = threadIdx.x;
    const int bh   = blockIdx.x;       // 0..3
    const int jh   = blockIdx.y;       // 0..1
    const int n    = blockIdx.z;       // 0..127
    const int wave = tid >> 6;
    const int lane = tid & 63;
    const int q    = lane >> 4;        // quad 0..3
    const int l    = lane & 15;

    // ---- DMA stage 64 KB M-half: 64 chunks of 1 KB (wave, iter) ----
    const unsigned short* src = Mbf + (size_t)n * (HID_ * HID_) + (size_t)jh * 32768;
    #pragma unroll
    for (int i = 0; i < 8; ++i) {
        const int c = i * 8 + wave;    // chunk id, wave-uniform
        __builtin_amdgcn_global_load_lds(
            (const __attribute__((address_space(1))) unsigned int*)(src + (size_t)c * 512 + lane * 8),
            (__attribute__((address_space(3))) unsigned int*)&Ms[c * 512],
            16, 0, 0);
    }

    // ---- afrag: x rows (bf16, pre-converted), full K, 2 row-blocks of 16 ----
    // A layout: A[m=lane&15][k=quad*8+j]
    bf16x8 afrag[2][8];
    #pragma unroll
    for (int rb = 0; rb < 2; ++rb) {
        const unsigned short* xr = xbf + (size_t)(bh * 256 + wave * 32 + rb * 16 + l) * HID_;
        #pragma unroll
        for (int kk = 0; kk < 8; ++kk)
            afrag[rb][kk] = *(const bf16x8*)(xr + kk * 32 + q * 8);
    }
    // v2 per lane per ct (j = jh*128 + ct*16 + l)
    float v2l[8];
    #pragma unroll
    for (int ct = 0; ct < 8; ++ct)
        v2l[ct] = v2[(size_t)n * HID_ + jh * 128 + ct * 16 + l];

    __syncthreads();   // drains the DMA (vmcnt) + the only barrier

    float part[8];
    #pragma unroll
    for (int i = 0; i < 8; ++i) part[i] = 0.f;

    // epilogue x source: row (bh*256 + wave*32 + q*4 + r + rb*16), col (jh*128 + ct*16 + l)
    const size_t xbase = (size_t)(bh * 256 + wave * 32 + q * 4) * HID_ + jh * 128 + l;

    #pragma unroll
    for (int ct = 0; ct < 8; ++ct) {
        // hoist fp32 x loads for the fused epilogue
        float xl[8];
        #pragma unroll
        for (int rb = 0; rb < 2; ++rb)
            #pragma unroll
            for (int r = 0; r < 4; ++r)
                xl[rb * 4 + r] = xp[xbase + (size_t)(rb * 16 + r) * HID_ + ct * 16];

        f32x4 acc0 = {0.f,0.f,0.f,0.f}, acc1 = {0.f,0.f,0.f,0.f};
        #pragma unroll
        for (int kk = 0; kk < 8; ++kk) {
            // swizzled read: row jr=ct*16+l, granule (kk*4+q)^((l&7)<<2)  -> 2-way banks (free)
            const bf16x8 bfrag = *(const bf16x8*)&Ms[(ct * 16 + l) * HID_ +
                                                     (((kk * 4 + q) ^ ((l & 7) << 2)) << 3)];
            acc0 = __builtin_amdgcn_mfma_f32_16x16x32_bf16(afrag[0][kk], bfrag, acc0, 0, 0, 0);
            acc1 = __builtin_amdgcn_mfma_f32_16x16x32_bf16(afrag[1][kk], bfrag, acc1, 0, 0, 0);
        }
        // fused epilogue: part += (T - v2) * x   (C/D layout: col=lane&15, row=quad*4+reg)
        const float vv = v2l[ct];
        #pragma unroll
        for (int r = 0; r < 4; ++r) {
            part[r]     += (acc0[r] - vv) * xl[r];
            part[4 + r] += (acc1[r] - vv) * xl[4 + r];
        }
    }

    // reduce across the 16 col-lanes of each quad
    #pragma unroll
    for (int i = 0; i < 8; ++i) {
        float v = part[i];
        v += __shfl_xor(v, 1);
        v += __shfl_xor(v, 2);
        v += __shfl_xor(v, 4);
        v += __shfl_xor(v, 8);
        part[i] = v;
    }
    if (l == 0) {
        float* pb = p + (size_t)jh * (B_ * N_);
        #pragma unroll
        for (int i = 0; i < 8; ++i) {
            const int row = bh * 256 + wave * 32 + (i >> 2) * 16 + q * 4 + (i & 3);
            pb[(size_t)row * N_ + n] = part[i];
        }
    }
}

// ---------------- finalize (+fused loss): distmat = sqrt(p0 + p1 + c[n] + 1e-12),
// loss partial = sum of label-selected entries (exactly 2 per 256-thread block),
// atomicAdd'ed /B onto out[0] (pre-initialized with clip residue by prep).
__global__ __launch_bounds__(256) void finalize_kernel(
    const float* __restrict__ p, const float* __restrict__ cpart,
    const int* __restrict__ labels, float* __restrict__ out)
{
    __shared__ float sc[128];
    __shared__ float ls[4];
    const int t = threadIdx.x;
    if (t < 128) {
        float s = 0.f;
        #pragma unroll
        for (int g = 0; g < 8; ++g) s += cpart[t * 8 + g];
        sc[t] = s;
    }
    __syncthreads();
    const int i = blockIdx.x * 256 + t;             // 0..131071
    const int n = i & (N_ - 1);
    const int b = i >> 7;
    const float d = sqrtf(p[i] + p[B_ * N_ + i] + sc[n] + 1e-12f);
    out[1 + i] = d;
    float sel = (labels[b] == n) ? d : 0.f;
    #pragma unroll
    for (int m = 1; m <= 32; m <<= 1) sel += __shfl_xor(sel, m);
    if ((t & 63) == 0) ls[t >> 6] = sel;
    __syncthreads();
    if (t == 0) atomicAdd(out, (ls[0] + ls[1] + ls[2] + ls[3]) * (1.f / (float)B_));
}

extern "C" void kernel_launch(void* const* d_in, const int* in_sizes, int n_in,
                              void* d_out, int out_size, void* d_ws, size_t ws_size,
                              hipStream_t stream) {
    const float* x      = (const float*)d_in[0];
    const int*   labels = (const int*)d_in[1];
    const float* W      = (const float*)d_in[2];
    const float* bias   = (const float*)d_in[3];
    const float* means  = (const float*)d_in[4];
    const float* invcov = (const float*)d_in[5];
    float* out = (float*)d_out;

    // workspace carve-up (~19.5 MB total)
    char* ws = (char*)d_ws;
    unsigned short* Mbf   = (unsigned short*)(ws);               // 16,777,216 B
    float*          xp    = (float*)         (ws + 16777216);    //  1,048,576 B
    unsigned short* xbf   = (unsigned short*)(ws + 17825792);    //    524,288 B
    float*          v2    = (float*)         (ws + 18350080);    //    131,072 B
    float*          cpart = (float*)         (ws + 18481152);    //      4,096 B
    float*          p     = (float*)         (ws + 18489344);    //  1,048,576 B

    constexpr int DIST_LDS = 128 * HID_ * 2;   // 65536 B dynamic LDS
    (void)hipFuncSetAttribute((const void*)dist_kernel,
                              hipFuncAttributeMaxDynamicSharedMemorySize, DIST_LDS);

    prep_kernel<<<dim3(1152), 512, 0, stream>>>(x, W, bias, means, invcov,
                                                xp, xbf, Mbf, v2, cpart, out);
    dist_kernel<<<dim3(4, 2, N_), 512, DIST_LDS, stream>>>(xp, xbf, Mbf, v2, p);
    finalize_kernel<<<dim3((B_ * N_) / 256), 256, 0, stream>>>(p, cpart, labels, out);
}